// Round 1
// baseline (224.121 us; speedup 1.0000x reference)
//
#include <hip/hip_runtime.h>

// Problem constants (b=8, h=w=32, m=8 heads, d=64, c=512)
#define Bn 8
#define Mh 8
#define Dd 64
#define Cc 512
#define HW 1024
#define BM 64            // Bn*Mh
#define LOG2E 1.44269504f

typedef __attribute__((ext_vector_type(8))) short bf16x8;
typedef __attribute__((ext_vector_type(4))) float f32x4;

__device__ __forceinline__ unsigned short f2bf(float f) {
  unsigned int u = __builtin_bit_cast(unsigned int, f);
  u += 0x7fffu + ((u >> 16) & 1u);
  return (unsigned short)(u >> 16);
}

// ---------------------------------------------------------------------------
// K1: QKV projection. One wave handles 8 (head,pos) items; W (64x192) in LDS.
// Writes Q (pre-scaled 1/8), K, V as bf16 in layout [bm][pos][d].
// ---------------------------------------------------------------------------
__global__ __launch_bounds__(256) void qkv_kernel(
    const float* __restrict__ x, const float* __restrict__ w,
    const float* __restrict__ bqkv,
    unsigned short* __restrict__ Q, unsigned short* __restrict__ K,
    unsigned short* __restrict__ V) {
  __shared__ float Wl[64 * 192];
  int t = threadIdx.x;
#pragma unroll
  for (int i = 0; i < 48; ++i) Wl[t + i * 256] = w[t + i * 256];
  __syncthreads();
  int lane = t & 63, wv = t >> 6;
  int base = blockIdx.x * 32 + wv * 8;  // item = bm*1024 + pos
  float xv[8];
#pragma unroll
  for (int it = 0; it < 8; ++it) {
    int item = base + it;
    int bm = item >> 10, pos = item & 1023;
    int bb = bm >> 3, mm = bm & 7;
    xv[it] = x[(size_t)(bb * HW + pos) * Cc + mm * Dd + lane];
  }
  float bq = bqkv[3 * lane + 0], bk = bqkv[3 * lane + 1], bv = bqkv[3 * lane + 2];
  float aq[8], ak[8], av[8];
#pragma unroll
  for (int it = 0; it < 8; ++it) { aq[it] = bq; ak[it] = bk; av[it] = bv; }
#pragma unroll
  for (int e = 0; e < 64; ++e) {
    float w0 = Wl[e * 192 + 3 * lane + 0];
    float w1 = Wl[e * 192 + 3 * lane + 1];
    float w2 = Wl[e * 192 + 3 * lane + 2];
#pragma unroll
    for (int it = 0; it < 8; ++it) {
      float xe = __shfl(xv[it], e);
      aq[it] = fmaf(xe, w0, aq[it]);
      ak[it] = fmaf(xe, w1, ak[it]);
      av[it] = fmaf(xe, w2, av[it]);
    }
  }
#pragma unroll
  for (int it = 0; it < 8; ++it) {
    size_t o = (size_t)(base + it) * Dd + lane;
    Q[o] = f2bf(aq[it] * 0.125f);   // q / sqrt(64)
    K[o] = f2bf(ak[it]);
    V[o] = f2bf(av[it]);
  }
}

// ---------------------------------------------------------------------------
// K2: flash attention with relative-position bias.
// Block: one (bm, 64-row i-tile). 4 waves x 16 rows. mfma_f32_16x16x32_bf16.
// Frag layouts: A[i][k]: i=lane&15, k=(lane>>4)*8+e (contiguous 8).
//               B[k][n]: n=lane&15, k=(lane>>4)*8+e.
//               D[i][j]: j=lane&15, i=(lane>>4)*4+reg.
// LDS tiles XOR-swizzled (^(row&7)<<3 in ushort units) for conflict-free b128.
// ---------------------------------------------------------------------------
__global__ __launch_bounds__(256) void attn_kernel(
    const unsigned short* __restrict__ Q, const unsigned short* __restrict__ K,
    const unsigned short* __restrict__ V, const float* __restrict__ pe,
    float* __restrict__ O) {
  __shared__ unsigned short Kt[64 * 64];   // [j][e] swizzled
  __shared__ unsigned short Vt[64 * 64];   // [d][j] swizzled (transposed V)
  __shared__ unsigned short Pl[4][16 * 64];// per-wave P tile [i][j] swizzled
  __shared__ float pes[3969];
  int t = threadIdx.x, lane = t & 63, wv = t >> 6;
  int bm = blockIdx.x >> 4;
  int i0 = (blockIdx.x & 15) * 64;
  for (int i = t; i < 3969; i += 256) pes[i] = pe[i];
  int c = lane & 15, r4 = lane >> 4;

  // Q A-frags (rows i0+wv*16+c, k-chunks 0 and 1), straight from global
  const unsigned short* Qb =
      Q + ((size_t)bm * HW + i0 + wv * 16 + c) * Dd + r4 * 8;
  bf16x8 qa0 = *(const bf16x8*)(Qb);
  bf16x8 qa1 = *(const bf16x8*)(Qb + 32);

  f32x4 oacc[4];
  float m_run[4], l_run[4];
#pragma unroll
  for (int r = 0; r < 4; ++r) {
    oacc[r] = {0.f, 0.f, 0.f, 0.f};
    m_run[r] = -__builtin_inff();
    l_run[r] = 0.f;
  }
  const unsigned short* Kg = K + (size_t)bm * HW * Dd;
  const unsigned short* Vg = V + (size_t)bm * HW * Dd;
  int irow_base = i0 + wv * 16 + r4 * 4;

  for (int jt = 0; jt < 16; ++jt) {
    int j0 = jt * 64;
    // stage K tile (b128, swizzled)
#pragma unroll
    for (int rep = 0; rep < 2; ++rep) {
      int cid = t + rep * 256;
      int row = cid >> 3, c8 = (cid & 7) * 8;
      bf16x8 val = *(const bf16x8*)(Kg + (size_t)(j0 + row) * Dd + c8);
      *(bf16x8*)&Kt[(row * 64 + c8) ^ ((row & 7) << 3)] = val;
    }
    // stage V tile transposed: Vt[d][j] = V[j0+j][d]
#pragma unroll
    for (int rep = 0; rep < 16; ++rep) {
      int j = wv * 16 + rep;
      unsigned short val = Vg[(size_t)(j0 + j) * Dd + lane];
      Vt[(lane * 64 + j) ^ ((lane & 7) << 3)] = val;
    }
    __syncthreads();

    // QK^T : S[16 x 64] per wave
    f32x4 sacc[4];
#pragma unroll
    for (int jf = 0; jf < 4; ++jf) sacc[jf] = {0.f, 0.f, 0.f, 0.f};
#pragma unroll
    for (int jf = 0; jf < 4; ++jf) {
      int row = jf * 16 + c;
      int sw = (row & 7) << 3;
      bf16x8 kb0 = *(const bf16x8*)&Kt[(row * 64 + r4 * 8) ^ sw];
      bf16x8 kb1 = *(const bf16x8*)&Kt[(row * 64 + 32 + r4 * 8) ^ sw];
      sacc[jf] = __builtin_amdgcn_mfma_f32_16x16x32_bf16(qa0, kb0, sacc[jf], 0, 0, 0);
      sacc[jf] = __builtin_amdgcn_mfma_f32_16x16x32_bf16(qa1, kb1, sacc[jf], 0, 0, 0);
    }

    // bias + online softmax
    float rowmax[4];
#pragma unroll
    for (int reg = 0; reg < 4; ++reg) {
      int row_abs = irow_base + reg;
      int yi = row_abs >> 5, xi = row_abs & 31;
      float mx = -__builtin_inff();
#pragma unroll
      for (int jf = 0; jf < 4; ++jf) {
        int j_abs = j0 + jf * 16 + c;
        int yj = j_abs >> 5, xj = j_abs & 31;
        float s = sacc[jf][reg] + pes[63 * (yj - yi + 31) + (xj - xi + 31)];
        sacc[jf][reg] = s;
        mx = fmaxf(mx, s);
      }
      rowmax[reg] = mx;
    }
#pragma unroll
    for (int step = 1; step < 16; step <<= 1) {
#pragma unroll
      for (int reg = 0; reg < 4; ++reg)
        rowmax[reg] = fmaxf(rowmax[reg], __shfl_xor(rowmax[reg], step));
    }
    float scale[4], psum[4];
#pragma unroll
    for (int reg = 0; reg < 4; ++reg) {
      float mnew = fmaxf(m_run[reg], rowmax[reg]);
      scale[reg] = exp2f((m_run[reg] - mnew) * LOG2E);
      float ps = 0.f;
#pragma unroll
      for (int jf = 0; jf < 4; ++jf) {
        float p = exp2f((sacc[jf][reg] - mnew) * LOG2E);
        sacc[jf][reg] = p;
        ps += p;
      }
      psum[reg] = ps;
      m_run[reg] = mnew;
    }
#pragma unroll
    for (int step = 1; step < 16; step <<= 1) {
#pragma unroll
      for (int reg = 0; reg < 4; ++reg)
        psum[reg] += __shfl_xor(psum[reg], step);
    }
#pragma unroll
    for (int reg = 0; reg < 4; ++reg) {
      l_run[reg] = l_run[reg] * scale[reg] + psum[reg];
#pragma unroll
      for (int nf = 0; nf < 4; ++nf) oacc[nf][reg] *= scale[reg];
    }
    // write P (bf16) to per-wave LDS tile, swizzled
#pragma unroll
    for (int reg = 0; reg < 4; ++reg) {
      int row = r4 * 4 + reg;
      int sw = (row & 7) << 3;
#pragma unroll
      for (int jf = 0; jf < 4; ++jf) {
        Pl[wv][(row * 64 + jf * 16 + c) ^ sw] = f2bf(sacc[jf][reg]);
      }
    }
    __syncthreads();

    // P·V : O[16 x 64] accumulate
#pragma unroll
    for (int jk = 0; jk < 2; ++jk) {
      bf16x8 pa = *(const bf16x8*)&Pl[wv][(c * 64 + jk * 32 + r4 * 8) ^ ((c & 7) << 3)];
#pragma unroll
      for (int nf = 0; nf < 4; ++nf) {
        int vrow = nf * 16 + c;
        bf16x8 vb = *(const bf16x8*)&Vt[(vrow * 64 + jk * 32 + r4 * 8) ^ ((vrow & 7) << 3)];
        oacc[nf] = __builtin_amdgcn_mfma_f32_16x16x32_bf16(pa, vb, oacc[nf], 0, 0, 0);
      }
    }
    __syncthreads();
  }

  // epilogue: normalize, store fp32 O [bm][pos][d]
#pragma unroll
  for (int reg = 0; reg < 4; ++reg) {
    float inv = 1.f / l_run[reg];
    int row = irow_base + reg;
#pragma unroll
    for (int nf = 0; nf < 4; ++nf) {
      O[((size_t)bm * HW + row) * Dd + nf * 16 + c] = oacc[nf][reg] * inv;
    }
  }
}

// ---------------------------------------------------------------------------
// K3: output projection. Block: 16 positions x 512 channels; O rows in LDS.
// ---------------------------------------------------------------------------
__global__ __launch_bounds__(256) void proj_kernel(
    const float* __restrict__ O, const float* __restrict__ W,
    const float* __restrict__ bias, float* __restrict__ out) {
  __shared__ float Or[16 * 512];
  int t = threadIdx.x;
  int bp0 = blockIdx.x * 16;  // flat (b,pos)
  for (int idx = t; idx < 16 * 512; idx += 256) {
    int p = idx >> 9, ch = idx & 511;
    int bp = bp0 + p, b = bp >> 10, pos = bp & 1023;
    Or[idx] = O[((size_t)(b * Mh + (ch >> 6)) * HW + pos) * Dd + (ch & 63)];
  }
  __syncthreads();
  float acc0[16], acc1[16];
  float bb0 = bias[t], bb1 = bias[t + 256];
#pragma unroll
  for (int p = 0; p < 16; ++p) { acc0[p] = bb0; acc1[p] = bb1; }
  for (int e = 0; e < 512; e += 4) {
    float wA0 = W[(size_t)(e + 0) * 512 + t], wB0 = W[(size_t)(e + 0) * 512 + t + 256];
    float wA1 = W[(size_t)(e + 1) * 512 + t], wB1 = W[(size_t)(e + 1) * 512 + t + 256];
    float wA2 = W[(size_t)(e + 2) * 512 + t], wB2 = W[(size_t)(e + 2) * 512 + t + 256];
    float wA3 = W[(size_t)(e + 3) * 512 + t], wB3 = W[(size_t)(e + 3) * 512 + t + 256];
#pragma unroll
    for (int p = 0; p < 16; ++p) {
      f32x4 ov = *(const f32x4*)&Or[p * 512 + e];
      acc0[p] = fmaf(ov[0], wA0, fmaf(ov[1], wA1, fmaf(ov[2], wA2, fmaf(ov[3], wA3, acc0[p]))));
      acc1[p] = fmaf(ov[0], wB0, fmaf(ov[1], wB1, fmaf(ov[2], wB2, fmaf(ov[3], wB3, acc1[p]))));
    }
  }
#pragma unroll
  for (int p = 0; p < 16; ++p) {
    size_t o = (size_t)(bp0 + p) * 512;
    out[o + t] = acc0[p];
    out[o + t + 256] = acc1[p];
  }
}

extern "C" void kernel_launch(void* const* d_in, const int* in_sizes, int n_in,
                              void* d_out, int out_size, void* d_ws, size_t ws_size,
                              hipStream_t stream) {
  const float* x      = (const float*)d_in[0];
  const float* qkv_w  = (const float*)d_in[1];
  const float* qkv_b  = (const float*)d_in[2];
  const float* pos_emb= (const float*)d_in[3];
  const float* ht_w   = (const float*)d_in[4];
  const float* ht_b   = (const float*)d_in[5];
  float* out = (float*)d_out;

  const size_t NQ = (size_t)BM * HW * Dd;  // 4,194,304 elements
  unsigned short* Qw = (unsigned short*)d_ws;
  unsigned short* Kw = Qw + NQ;
  unsigned short* Vw = Kw + NQ;
  float* Ow = (float*)(Vw + NQ);           // 24 MB offset, fp32 O (16 MB)

  hipLaunchKernelGGL(qkv_kernel, dim3(2048), dim3(256), 0, stream,
                     x, qkv_w, qkv_b, Qw, Kw, Vw);
  hipLaunchKernelGGL(attn_kernel, dim3(1024), dim3(256), 0, stream,
                     Qw, Kw, Vw, pos_emb, Ow);
  hipLaunchKernelGGL(proj_kernel, dim3(512), dim3(256), 0, stream,
                     Ow, ht_w, ht_b, out);
}

// Round 2
// 133.709 us; speedup vs baseline: 1.6762x; 1.6762x over previous
//
#include <hip/hip_runtime.h>

// Problem constants (b=8, h=w=32, m=8 heads, d=64, c=512)
#define Dd 64
#define Cc 512
#define HW 1024
#define BM 64            // b*m
#define LOG2E 1.44269504f

typedef __attribute__((ext_vector_type(8))) short bf16x8;
typedef __attribute__((ext_vector_type(4))) short bf16x4;
typedef __attribute__((ext_vector_type(4))) float f32x4;

__device__ __forceinline__ unsigned short f2bf(float f) {
  unsigned int u = __builtin_bit_cast(unsigned int, f);
  u += 0x7fffu + ((u >> 16) & 1u);
  return (unsigned short)(u >> 16);
}

// 16B-granular XOR swizzle for [rows][64 bf16] LDS tiles (row stride 128B).
// byte = row*128 + (colbyte ^ ((row&7)<<4)). Conflict-free for b128 reads of
// column-slices (G4) and slot-balanced for b64/b128 staged writes.
__device__ __forceinline__ int swz(int row, int cb) {
  return row * 128 + (cb ^ ((row & 7) << 4));
}

// ---------------------------------------------------------------------------
// K1: QKV projection. One wave handles 8 (head,pos) items; W (64x192) in LDS.
// Writes Q (pre-scaled 1/8), K, V as bf16 in layout [bm][pos][d].
// ---------------------------------------------------------------------------
__global__ __launch_bounds__(256) void qkv_kernel(
    const float* __restrict__ x, const float* __restrict__ w,
    const float* __restrict__ bqkv,
    unsigned short* __restrict__ Q, unsigned short* __restrict__ K,
    unsigned short* __restrict__ V) {
  __shared__ float Wl[64 * 192];
  int t = threadIdx.x;
#pragma unroll
  for (int i = 0; i < 48; ++i) Wl[t + i * 256] = w[t + i * 256];
  __syncthreads();
  int lane = t & 63, wv = t >> 6;
  int base = blockIdx.x * 32 + wv * 8;  // item = bm*1024 + pos
  float xv[8];
#pragma unroll
  for (int it = 0; it < 8; ++it) {
    int item = base + it;
    int bm = item >> 10, pos = item & 1023;
    int bb = bm >> 3, mm = bm & 7;
    xv[it] = x[(size_t)(bb * HW + pos) * Cc + mm * Dd + lane];
  }
  float bq = bqkv[3 * lane + 0], bk = bqkv[3 * lane + 1], bv = bqkv[3 * lane + 2];
  float aq[8], ak[8], av[8];
#pragma unroll
  for (int it = 0; it < 8; ++it) { aq[it] = bq; ak[it] = bk; av[it] = bv; }
#pragma unroll
  for (int e = 0; e < 64; ++e) {
    float w0 = Wl[e * 192 + 3 * lane + 0];
    float w1 = Wl[e * 192 + 3 * lane + 1];
    float w2 = Wl[e * 192 + 3 * lane + 2];
#pragma unroll
    for (int it = 0; it < 8; ++it) {
      float xe = __shfl(xv[it], e);
      aq[it] = fmaf(xe, w0, aq[it]);
      ak[it] = fmaf(xe, w1, ak[it]);
      av[it] = fmaf(xe, w2, av[it]);
    }
  }
#pragma unroll
  for (int it = 0; it < 8; ++it) {
    size_t o = (size_t)(base + it) * Dd + lane;
    Q[o] = f2bf(aq[it] * 0.125f);   // q / sqrt(64)
    K[o] = f2bf(ak[it]);
    V[o] = f2bf(av[it]);
  }
}

// ---------------------------------------------------------------------------
// K2: flash attention with relative-position bias.
// Block: one (bm, 128-row i-tile). 8 waves x 16 rows. mfma_f32_16x16x32_bf16.
// Waves 0-3 stage K (b128), waves 4-7 stage V via 4x4 in-reg transpose (b64).
// T14: next tile's global loads issued after barrier#2, drained at barrier#1.
// Output O in bf16.
// ---------------------------------------------------------------------------
__global__ __launch_bounds__(512) void attn_kernel(
    const unsigned short* __restrict__ Q, const unsigned short* __restrict__ K,
    const unsigned short* __restrict__ V, const float* __restrict__ pe,
    unsigned short* __restrict__ O) {
  __shared__ unsigned short Kt[64 * 64];    // [j][e] swizzled
  __shared__ unsigned short Vt[64 * 64];    // [d][j] swizzled (transposed V)
  __shared__ unsigned short Pl[8][16 * 64]; // per-wave P tile [i][j] swizzled
  __shared__ float pes[3969];
  char* KtB = (char*)Kt;
  char* VtB = (char*)Vt;
  int t = threadIdx.x, lane = t & 63, wv = t >> 6;
  int bm = blockIdx.x >> 3;
  int i0 = (blockIdx.x & 7) * 128;
  for (int i = t; i < 3969; i += 512) pes[i] = pe[i];
  int c = lane & 15, r4 = lane >> 4;
  char* PlB = (char*)&Pl[wv][0];

  const unsigned short* Qb =
      Q + ((size_t)bm * HW + i0 + wv * 16 + c) * Dd + r4 * 8;
  bf16x8 qa0 = *(const bf16x8*)(Qb);
  bf16x8 qa1 = *(const bf16x8*)(Qb + 32);

  f32x4 oacc[4];
  float m_run[4], l_run[4];
#pragma unroll
  for (int r = 0; r < 4; ++r) {
    oacc[r] = {0.f, 0.f, 0.f, 0.f};
    m_run[r] = -__builtin_inff();
    l_run[r] = 0.f;
  }
  const unsigned short* Kg = K + (size_t)bm * HW * Dd;
  const unsigned short* Vg = V + (size_t)bm * HW * Dd;
  int irow_base = i0 + wv * 16 + r4 * 4;

  // staging roles
  const bool isK = (wv < 4);
  int krow = t >> 3, kc8 = t & 7;          // K threads
  int v_ = t & 255, dt = v_ & 15, jt4 = v_ >> 4;  // V threads
  bf16x8 kreg0, kreg1;
  bf16x4 vreg[4];

  auto issue = [&](int j0) {
    if (isK) {
      kreg0 = *(const bf16x8*)(Kg + (size_t)(j0 + krow) * Dd + kc8 * 8);
      kreg1 = *(const bf16x8*)(Kg + (size_t)(j0 + 32 + krow) * Dd + kc8 * 8);
    } else {
#pragma unroll
      for (int r = 0; r < 4; ++r)
        vreg[r] = *(const bf16x4*)(Vg + (size_t)(j0 + jt4 * 4 + r) * Dd + dt * 4);
    }
  };

  issue(0);
  for (int jt = 0; jt < 16; ++jt) {
    int j0 = jt * 64;
    __syncthreads();  // prev compute done reading LDS; drains prefetch loads
    if (isK) {
      *(bf16x8*)(KtB + swz(krow, kc8 * 16)) = kreg0;
      *(bf16x8*)(KtB + swz(krow + 32, kc8 * 16)) = kreg1;
    } else {
#pragma unroll
      for (int e = 0; e < 4; ++e) {
        bf16x4 vt = {vreg[0][e], vreg[1][e], vreg[2][e], vreg[3][e]};
        *(bf16x4*)(VtB + swz(dt * 4 + e, jt4 * 8)) = vt;
      }
    }
    __syncthreads();  // LDS tiles ready
    if (jt < 15) issue(j0 + 64);  // overlap next loads with compute (T14)

    // QK^T : S[16 x 64] per wave
    f32x4 sacc[4];
#pragma unroll
    for (int jf = 0; jf < 4; ++jf) sacc[jf] = {0.f, 0.f, 0.f, 0.f};
#pragma unroll
    for (int jf = 0; jf < 4; ++jf) {
      int row = jf * 16 + c;
      bf16x8 kb0 = *(const bf16x8*)(KtB + swz(row, r4 * 16));
      bf16x8 kb1 = *(const bf16x8*)(KtB + swz(row, 64 + r4 * 16));
      sacc[jf] = __builtin_amdgcn_mfma_f32_16x16x32_bf16(qa0, kb0, sacc[jf], 0, 0, 0);
      sacc[jf] = __builtin_amdgcn_mfma_f32_16x16x32_bf16(qa1, kb1, sacc[jf], 0, 0, 0);
    }

    // bias (hoisted index base: addr = base + c) + online softmax
    float rowmax[4];
#pragma unroll
    for (int reg = 0; reg < 4; ++reg) {
      int row_abs = irow_base + reg;
      int yi = row_abs >> 5, xi = row_abs & 31;
      int bj = (j0 >> 5) - yi + 31;
      float mx = -__builtin_inff();
#pragma unroll
      for (int jf = 0; jf < 4; ++jf) {
        int base = 63 * (bj + (jf >> 1)) + ((jf & 1) * 16 - xi + 31);
        float s = sacc[jf][reg] + pes[base + c];
        sacc[jf][reg] = s;
        mx = fmaxf(mx, s);
      }
      rowmax[reg] = mx;
    }
#pragma unroll
    for (int step = 1; step < 16; step <<= 1) {
#pragma unroll
      for (int reg = 0; reg < 4; ++reg)
        rowmax[reg] = fmaxf(rowmax[reg], __shfl_xor(rowmax[reg], step));
    }
    float scale[4], psum[4];
#pragma unroll
    for (int reg = 0; reg < 4; ++reg) {
      float mnew = fmaxf(m_run[reg], rowmax[reg]);
      float ml = mnew * LOG2E;
      scale[reg] = __builtin_amdgcn_exp2f(m_run[reg] * LOG2E - ml);
      float ps = 0.f;
#pragma unroll
      for (int jf = 0; jf < 4; ++jf) {
        float p = __builtin_amdgcn_exp2f(fmaf(sacc[jf][reg], LOG2E, -ml));
        sacc[jf][reg] = p;
        ps += p;
      }
      psum[reg] = ps;
      m_run[reg] = mnew;
    }
#pragma unroll
    for (int step = 1; step < 16; step <<= 1) {
#pragma unroll
      for (int reg = 0; reg < 4; ++reg)
        psum[reg] += __shfl_xor(psum[reg], step);
    }
#pragma unroll
    for (int reg = 0; reg < 4; ++reg) {
      l_run[reg] = l_run[reg] * scale[reg] + psum[reg];
#pragma unroll
      for (int nf = 0; nf < 4; ++nf) oacc[nf][reg] *= scale[reg];
    }
    // write P (bf16) to per-wave LDS tile (wave-local: no barrier needed)
#pragma unroll
    for (int reg = 0; reg < 4; ++reg) {
      int row = r4 * 4 + reg;
#pragma unroll
      for (int jf = 0; jf < 4; ++jf) {
        *(unsigned short*)(PlB + swz(row, (jf * 16 + c) * 2)) =
            f2bf(sacc[jf][reg]);
      }
    }

    // P·V : O[16 x 64] accumulate
#pragma unroll
    for (int jk = 0; jk < 2; ++jk) {
      bf16x8 pa = *(const bf16x8*)(PlB + swz(c, jk * 64 + r4 * 16));
#pragma unroll
      for (int nf = 0; nf < 4; ++nf) {
        bf16x8 vb = *(const bf16x8*)(VtB + swz(nf * 16 + c, jk * 64 + r4 * 16));
        oacc[nf] = __builtin_amdgcn_mfma_f32_16x16x32_bf16(pa, vb, oacc[nf], 0, 0, 0);
      }
    }
  }

  // epilogue: normalize, store bf16 O [bm][pos][d]
#pragma unroll
  for (int reg = 0; reg < 4; ++reg) {
    float inv = 1.f / l_run[reg];
    int row = irow_base + reg;
#pragma unroll
    for (int nf = 0; nf < 4; ++nf) {
      O[((size_t)bm * HW + row) * Dd + nf * 16 + c] = f2bf(oacc[nf][reg] * inv);
    }
  }
}

// ---------------------------------------------------------------------------
// K3: output projection, bf16 MFMA. Block: 128 rows x 64 cols, 4 waves.
// K-loop over 8 chunks of 64 (= heads). W transposed into LDS via 4x4
// in-register transpose (fp32->bf16). Same T14 prefetch as attn.
// ---------------------------------------------------------------------------
__global__ __launch_bounds__(256) void proj_kernel(
    const unsigned short* __restrict__ O, const float* __restrict__ W,
    const float* __restrict__ bias, float* __restrict__ out) {
  __shared__ unsigned short Aq[128 * 64];  // [row][k] swizzled
  __shared__ unsigned short Bt[64 * 64];   // [n][k] swizzled
  char* AqB = (char*)Aq;
  char* BtB = (char*)Bt;
  int t = threadIdx.x, lane = t & 63, wv = t >> 6;
  int rb = blockIdx.x >> 3, n0 = (blockIdx.x & 7) * 64;
  int row0 = rb * 128;             // flat (b,pos); never crosses b
  int b = row0 >> 10, pos0 = row0 & 1023;
  int c = lane & 15, r4 = lane >> 4;
  int nt = t & 15, kt = t >> 4;    // B staging roles

  f32x4 acc[2][4];
#pragma unroll
  for (int g = 0; g < 2; ++g)
#pragma unroll
    for (int nf = 0; nf < 4; ++nf) acc[g][nf] = {0.f, 0.f, 0.f, 0.f};

  bf16x8 areg[4];
  f32x4 wreg[4];

  auto issue = [&](int m) {
#pragma unroll
    for (int rep = 0; rep < 4; ++rep) {
      int cid = t + rep * 256;
      int row = cid >> 3, c8 = cid & 7;
      areg[rep] = *(const bf16x8*)(O + ((size_t)(b * 8 + m) * HW + pos0 + row) * Dd + c8 * 8);
    }
#pragma unroll
    for (int r = 0; r < 4; ++r)
      wreg[r] = *(const f32x4*)(W + (size_t)(m * 64 + kt * 4 + r) * Cc + n0 + nt * 4);
  };

  issue(0);
  for (int m = 0; m < 8; ++m) {
    __syncthreads();
#pragma unroll
    for (int rep = 0; rep < 4; ++rep) {
      int cid = t + rep * 256;
      int row = cid >> 3, c8 = cid & 7;
      *(bf16x8*)(AqB + swz(row, c8 * 16)) = areg[rep];
    }
#pragma unroll
    for (int e = 0; e < 4; ++e) {
      bf16x4 bt = {(short)f2bf(wreg[0][e]), (short)f2bf(wreg[1][e]),
                   (short)f2bf(wreg[2][e]), (short)f2bf(wreg[3][e])};
      *(bf16x4*)(BtB + swz(nt * 4 + e, kt * 8)) = bt;
    }
    __syncthreads();
    if (m < 7) issue(m + 1);

#pragma unroll
    for (int kc = 0; kc < 2; ++kc) {
      bf16x8 a0 = *(const bf16x8*)(AqB + swz(wv * 32 + c, kc * 64 + r4 * 16));
      bf16x8 a1 = *(const bf16x8*)(AqB + swz(wv * 32 + 16 + c, kc * 64 + r4 * 16));
#pragma unroll
      for (int nf = 0; nf < 4; ++nf) {
        bf16x8 bb = *(const bf16x8*)(BtB + swz(nf * 16 + c, kc * 64 + r4 * 16));
        acc[0][nf] = __builtin_amdgcn_mfma_f32_16x16x32_bf16(a0, bb, acc[0][nf], 0, 0, 0);
        acc[1][nf] = __builtin_amdgcn_mfma_f32_16x16x32_bf16(a1, bb, acc[1][nf], 0, 0, 0);
      }
    }
  }

  float bv[4];
#pragma unroll
  for (int nf = 0; nf < 4; ++nf) bv[nf] = bias[n0 + nf * 16 + c];
#pragma unroll
  for (int g = 0; g < 2; ++g) {
#pragma unroll
    for (int reg = 0; reg < 4; ++reg) {
      int row = row0 + wv * 32 + g * 16 + r4 * 4 + reg;
#pragma unroll
      for (int nf = 0; nf < 4; ++nf)
        out[(size_t)row * Cc + n0 + nf * 16 + c] = acc[g][nf][reg] + bv[nf];
    }
  }
}

extern "C" void kernel_launch(void* const* d_in, const int* in_sizes, int n_in,
                              void* d_out, int out_size, void* d_ws, size_t ws_size,
                              hipStream_t stream) {
  const float* x      = (const float*)d_in[0];
  const float* qkv_w  = (const float*)d_in[1];
  const float* qkv_b  = (const float*)d_in[2];
  const float* pos_emb= (const float*)d_in[3];
  const float* ht_w   = (const float*)d_in[4];
  const float* ht_b   = (const float*)d_in[5];
  float* out = (float*)d_out;

  const size_t NQ = (size_t)BM * HW * Dd;  // 4,194,304 elements
  unsigned short* Qw = (unsigned short*)d_ws;
  unsigned short* Kw = Qw + NQ;
  unsigned short* Vw = Kw + NQ;
  unsigned short* Ow = Vw + NQ;            // bf16 O, 8 MB

  hipLaunchKernelGGL(qkv_kernel, dim3(2048), dim3(256), 0, stream,
                     x, qkv_w, qkv_b, Qw, Kw, Vw);
  hipLaunchKernelGGL(attn_kernel, dim3(512), dim3(512), 0, stream,
                     Qw, Kw, Vw, pos_emb, Ow);
  hipLaunchKernelGGL(proj_kernel, dim3(512), dim3(256), 0, stream,
                     Ow, ht_w, ht_b, out);
}

// Round 7
// 98.960 us; speedup vs baseline: 2.2647x; 1.3511x over previous
//
#include <hip/hip_runtime.h>

// Problem constants (b=8, h=w=32, m=8 heads, d=64, c=512)
#define Dd 64
#define Cc 512
#define HW 1024
#define BM 64            // b*m
#define LOG2E 1.44269504f

typedef __attribute__((ext_vector_type(8))) short bf16x8;
typedef __attribute__((ext_vector_type(4))) short bf16x4;
typedef __attribute__((ext_vector_type(4))) float f32x4;

__device__ __forceinline__ unsigned short f2bf(float f) {
  unsigned int u = __builtin_bit_cast(unsigned int, f);
  u += 0x7fffu + ((u >> 16) & 1u);
  return (unsigned short)(u >> 16);
}

__device__ __forceinline__ unsigned int pack2(float lo, float hi) {
  return (unsigned int)f2bf(lo) | ((unsigned int)f2bf(hi) << 16);
}

// 16B-granular XOR swizzle for [rows][64 bf16] LDS tiles (row stride 128B).
__device__ __forceinline__ int swz(int row, int cb) {
  return row * 128 + (cb ^ ((row & 7) << 4));
}

// ---------------------------------------------------------------------------
// K1 (NEW, f2bf-only): QKV projection as swapped MFMA GEMM.
// W'[k][n'] = qkv_w[k][3*dd+which], n' = which*64+dd (Q cols+bias 1/8).
// A-frags (W'^T) from LDS once; B-frags (x^T) converted in-reg; bias in C.
// ---------------------------------------------------------------------------
__global__ __launch_bounds__(256, 2) void qkv_kernel(
    const float* __restrict__ x, const float* __restrict__ w,
    const float* __restrict__ bqkv,
    unsigned short* __restrict__ Q, unsigned short* __restrict__ K,
    unsigned short* __restrict__ V) {
  __shared__ unsigned short Wt[192 * 64];  // [n'][k] swizzled
  __shared__ float bl[192];
  char* WtB = (char*)Wt;
  int t = threadIdx.x, lane = t & 63, wv = t >> 6;
  int c = lane & 15, r4 = lane >> 4;
  int bm = blockIdx.x >> 4;
  int pos0 = (blockIdx.x & 15) * 64;
  int bb = bm >> 3, mm = bm & 7;

  for (int idx = t; idx < 12288; idx += 256) {
    int k = idx / 192, col = idx - (idx / 192) * 192;
    int d3 = col / 3, which = col - d3 * 3;
    int np = which * 64 + d3;
    float v = w[idx];
    if (which == 0) v *= 0.125f;  // q / sqrt(64)
    *(unsigned short*)(WtB + np * 128 + ((k * 2) ^ ((np & 7) << 4))) = f2bf(v);
  }
  if (t < 192) {
    int d3 = t / 3, which = t - d3 * 3;
    float bvv = bqkv[t];
    if (which == 0) bvv *= 0.125f;
    bl[which * 64 + d3] = bvv;
  }
  __syncthreads();

  bf16x8 af[12][2];
#pragma unroll
  for (int nf = 0; nf < 12; ++nf) {
    int row = nf * 16 + c, sw = (row & 7) << 4;
#pragma unroll
    for (int kc = 0; kc < 2; ++kc)
      af[nf][kc] = *(const bf16x8*)(WtB + row * 128 + ((kc * 64 + r4 * 16) ^ sw));
  }
  f32x4 acc[12];
#pragma unroll
  for (int nf = 0; nf < 12; ++nf)
    acc[nf] = *(const f32x4*)&bl[nf * 16 + r4 * 4];

  int pos = pos0 + wv * 16 + c;
  const float* xr = x + (size_t)(bb * HW + pos) * Cc + mm * Dd;
  bf16x8 xb[2];
#pragma unroll
  for (int kc = 0; kc < 2; ++kc) {
    f32x4 lo = *(const f32x4*)(xr + kc * 32 + r4 * 8);
    f32x4 hi = *(const f32x4*)(xr + kc * 32 + r4 * 8 + 4);
    union { unsigned int u[4]; bf16x8 b; } cv;
    cv.u[0] = pack2(lo[0], lo[1]);
    cv.u[1] = pack2(lo[2], lo[3]);
    cv.u[2] = pack2(hi[0], hi[1]);
    cv.u[3] = pack2(hi[2], hi[3]);
    xb[kc] = cv.b;
  }
#pragma unroll
  for (int nf = 0; nf < 12; ++nf) {
    acc[nf] = __builtin_amdgcn_mfma_f32_16x16x32_bf16(af[nf][0], xb[0], acc[nf], 0, 0, 0);
    acc[nf] = __builtin_amdgcn_mfma_f32_16x16x32_bf16(af[nf][1], xb[1], acc[nf], 0, 0, 0);
  }
  size_t obase = ((size_t)bm * HW + pos) * Dd;
#pragma unroll
  for (int nf = 0; nf < 12; ++nf) {
    unsigned int d0 = pack2(acc[nf][0], acc[nf][1]);
    unsigned int d1 = pack2(acc[nf][2], acc[nf][3]);
    unsigned long long wd = (unsigned long long)d0 | ((unsigned long long)d1 << 32);
    unsigned short* dst = (nf < 4) ? Q : (nf < 8) ? K : V;
    *(unsigned long long*)(dst + obase + (nf & 3) * 16 + r4 * 4) = wd;
  }
}

// ---------------------------------------------------------------------------
// K2 (ROUND-2 VERBATIM, known-PASS): flash attention with rel-pos bias.
// Block: one (bm, 128-row i-tile). 8 waves x 16 rows. mfma_f32_16x16x32_bf16.
// ---------------------------------------------------------------------------
__global__ __launch_bounds__(512) void attn_kernel(
    const unsigned short* __restrict__ Q, const unsigned short* __restrict__ K,
    const unsigned short* __restrict__ V, const float* __restrict__ pe,
    unsigned short* __restrict__ O) {
  __shared__ unsigned short Kt[64 * 64];    // [j][e] swizzled
  __shared__ unsigned short Vt[64 * 64];    // [d][j] swizzled (transposed V)
  __shared__ unsigned short Pl[8][16 * 64]; // per-wave P tile [i][j] swizzled
  __shared__ float pes[3969];
  char* KtB = (char*)Kt;
  char* VtB = (char*)Vt;
  int t = threadIdx.x, lane = t & 63, wv = t >> 6;
  int bm = blockIdx.x >> 3;
  int i0 = (blockIdx.x & 7) * 128;
  for (int i = t; i < 3969; i += 512) pes[i] = pe[i];
  int c = lane & 15, r4 = lane >> 4;
  char* PlB = (char*)&Pl[wv][0];

  const unsigned short* Qb =
      Q + ((size_t)bm * HW + i0 + wv * 16 + c) * Dd + r4 * 8;
  bf16x8 qa0 = *(const bf16x8*)(Qb);
  bf16x8 qa1 = *(const bf16x8*)(Qb + 32);

  f32x4 oacc[4];
  float m_run[4], l_run[4];
#pragma unroll
  for (int r = 0; r < 4; ++r) {
    oacc[r] = {0.f, 0.f, 0.f, 0.f};
    m_run[r] = -__builtin_inff();
    l_run[r] = 0.f;
  }
  const unsigned short* Kg = K + (size_t)bm * HW * Dd;
  const unsigned short* Vg = V + (size_t)bm * HW * Dd;
  int irow_base = i0 + wv * 16 + r4 * 4;

  const bool isK = (wv < 4);
  int krow = t >> 3, kc8 = t & 7;
  int v_ = t & 255, dt = v_ & 15, jt4 = v_ >> 4;
  bf16x8 kreg0, kreg1;
  bf16x4 vreg[4];

  auto issue = [&](int j0) {
    if (isK) {
      kreg0 = *(const bf16x8*)(Kg + (size_t)(j0 + krow) * Dd + kc8 * 8);
      kreg1 = *(const bf16x8*)(Kg + (size_t)(j0 + 32 + krow) * Dd + kc8 * 8);
    } else {
#pragma unroll
      for (int r = 0; r < 4; ++r)
        vreg[r] = *(const bf16x4*)(Vg + (size_t)(j0 + jt4 * 4 + r) * Dd + dt * 4);
    }
  };

  issue(0);
  for (int jt = 0; jt < 16; ++jt) {
    int j0 = jt * 64;
    __syncthreads();
    if (isK) {
      *(bf16x8*)(KtB + swz(krow, kc8 * 16)) = kreg0;
      *(bf16x8*)(KtB + swz(krow + 32, kc8 * 16)) = kreg1;
    } else {
#pragma unroll
      for (int e = 0; e < 4; ++e) {
        bf16x4 vt = {vreg[0][e], vreg[1][e], vreg[2][e], vreg[3][e]};
        *(bf16x4*)(VtB + swz(dt * 4 + e, jt4 * 8)) = vt;
      }
    }
    __syncthreads();
    if (jt < 15) issue(j0 + 64);

    f32x4 sacc[4];
#pragma unroll
    for (int jf = 0; jf < 4; ++jf) sacc[jf] = {0.f, 0.f, 0.f, 0.f};
#pragma unroll
    for (int jf = 0; jf < 4; ++jf) {
      int row = jf * 16 + c;
      bf16x8 kb0 = *(const bf16x8*)(KtB + swz(row, r4 * 16));
      bf16x8 kb1 = *(const bf16x8*)(KtB + swz(row, 64 + r4 * 16));
      sacc[jf] = __builtin_amdgcn_mfma_f32_16x16x32_bf16(qa0, kb0, sacc[jf], 0, 0, 0);
      sacc[jf] = __builtin_amdgcn_mfma_f32_16x16x32_bf16(qa1, kb1, sacc[jf], 0, 0, 0);
    }

    float rowmax[4];
#pragma unroll
    for (int reg = 0; reg < 4; ++reg) {
      int row_abs = irow_base + reg;
      int yi = row_abs >> 5, xi = row_abs & 31;
      int bj = (j0 >> 5) - yi + 31;
      float mx = -__builtin_inff();
#pragma unroll
      for (int jf = 0; jf < 4; ++jf) {
        int base = 63 * (bj + (jf >> 1)) + ((jf & 1) * 16 - xi + 31);
        float s = sacc[jf][reg] + pes[base + c];
        sacc[jf][reg] = s;
        mx = fmaxf(mx, s);
      }
      rowmax[reg] = mx;
    }
#pragma unroll
    for (int step = 1; step < 16; step <<= 1) {
#pragma unroll
      for (int reg = 0; reg < 4; ++reg)
        rowmax[reg] = fmaxf(rowmax[reg], __shfl_xor(rowmax[reg], step));
    }
    float scale[4], psum[4];
#pragma unroll
    for (int reg = 0; reg < 4; ++reg) {
      float mnew = fmaxf(m_run[reg], rowmax[reg]);
      float ml = mnew * LOG2E;
      scale[reg] = __builtin_amdgcn_exp2f(m_run[reg] * LOG2E - ml);
      float ps = 0.f;
#pragma unroll
      for (int jf = 0; jf < 4; ++jf) {
        float p = __builtin_amdgcn_exp2f(fmaf(sacc[jf][reg], LOG2E, -ml));
        sacc[jf][reg] = p;
        ps += p;
      }
      psum[reg] = ps;
      m_run[reg] = mnew;
    }
#pragma unroll
    for (int step = 1; step < 16; step <<= 1) {
#pragma unroll
      for (int reg = 0; reg < 4; ++reg)
        psum[reg] += __shfl_xor(psum[reg], step);
    }
#pragma unroll
    for (int reg = 0; reg < 4; ++reg) {
      l_run[reg] = l_run[reg] * scale[reg] + psum[reg];
#pragma unroll
      for (int nf = 0; nf < 4; ++nf) oacc[nf][reg] *= scale[reg];
    }
#pragma unroll
    for (int reg = 0; reg < 4; ++reg) {
      int row = r4 * 4 + reg;
#pragma unroll
      for (int jf = 0; jf < 4; ++jf) {
        *(unsigned short*)(PlB + swz(row, (jf * 16 + c) * 2)) =
            f2bf(sacc[jf][reg]);
      }
    }

#pragma unroll
    for (int jk = 0; jk < 2; ++jk) {
      bf16x8 pa = *(const bf16x8*)(PlB + swz(c, jk * 64 + r4 * 16));
#pragma unroll
      for (int nf = 0; nf < 4; ++nf) {
        bf16x8 vb = *(const bf16x8*)(VtB + swz(nf * 16 + c, jk * 64 + r4 * 16));
        oacc[nf] = __builtin_amdgcn_mfma_f32_16x16x32_bf16(pa, vb, oacc[nf], 0, 0, 0);
      }
    }
  }

#pragma unroll
  for (int reg = 0; reg < 4; ++reg) {
    float inv = 1.f / l_run[reg];
    int row = irow_base + reg;
#pragma unroll
    for (int nf = 0; nf < 4; ++nf) {
      O[((size_t)bm * HW + row) * Dd + nf * 16 + c] = f2bf(oacc[nf][reg] * inv);
    }
  }
}

// ---------------------------------------------------------------------------
// K3 (ROUND-2 VERBATIM, known-PASS): output projection, bf16 MFMA.
// Block: 128 rows x 64 cols, 4 waves; W transposed into LDS via 4x4 in-reg
// transpose (fp32->bf16); T14 prefetch.
// ---------------------------------------------------------------------------
__global__ __launch_bounds__(256) void proj_kernel(
    const unsigned short* __restrict__ O, const float* __restrict__ W,
    const float* __restrict__ bias, float* __restrict__ out) {
  __shared__ unsigned short Aq[128 * 64];  // [row][k] swizzled
  __shared__ unsigned short Bt[64 * 64];   // [n][k] swizzled
  char* AqB = (char*)Aq;
  char* BtB = (char*)Bt;
  int t = threadIdx.x, lane = t & 63, wv = t >> 6;
  int rb = blockIdx.x >> 3, n0 = (blockIdx.x & 7) * 64;
  int row0 = rb * 128;             // flat (b,pos); never crosses b
  int b = row0 >> 10, pos0 = row0 & 1023;
  int c = lane & 15, r4 = lane >> 4;
  int nt = t & 15, kt = t >> 4;    // B staging roles

  f32x4 acc[2][4];
#pragma unroll
  for (int g = 0; g < 2; ++g)
#pragma unroll
    for (int nf = 0; nf < 4; ++nf) acc[g][nf] = {0.f, 0.f, 0.f, 0.f};

  bf16x8 areg[4];
  f32x4 wreg[4];

  auto issue = [&](int m) {
#pragma unroll
    for (int rep = 0; rep < 4; ++rep) {
      int cid = t + rep * 256;
      int row = cid >> 3, c8 = cid & 7;
      areg[rep] = *(const bf16x8*)(O + ((size_t)(b * 8 + m) * HW + pos0 + row) * Dd + c8 * 8);
    }
#pragma unroll
    for (int r = 0; r < 4; ++r)
      wreg[r] = *(const f32x4*)(W + (size_t)(m * 64 + kt * 4 + r) * Cc + n0 + nt * 4);
  };

  issue(0);
  for (int m = 0; m < 8; ++m) {
    __syncthreads();
#pragma unroll
    for (int rep = 0; rep < 4; ++rep) {
      int cid = t + rep * 256;
      int row = cid >> 3, c8 = cid & 7;
      *(bf16x8*)(AqB + swz(row, c8 * 16)) = areg[rep];
    }
#pragma unroll
    for (int e = 0; e < 4; ++e) {
      bf16x4 bt = {(short)f2bf(wreg[0][e]), (short)f2bf(wreg[1][e]),
                   (short)f2bf(wreg[2][e]), (short)f2bf(wreg[3][e])};
      *(bf16x4*)(BtB + swz(nt * 4 + e, kt * 8)) = bt;
    }
    __syncthreads();
    if (m < 7) issue(m + 1);

#pragma unroll
    for (int kc = 0; kc < 2; ++kc) {
      bf16x8 a0 = *(const bf16x8*)(AqB + swz(wv * 32 + c, kc * 64 + r4 * 16));
      bf16x8 a1 = *(const bf16x8*)(AqB + swz(wv * 32 + 16 + c, kc * 64 + r4 * 16));
#pragma unroll
      for (int nf = 0; nf < 4; ++nf) {
        bf16x8 bb = *(const bf16x8*)(BtB + swz(nf * 16 + c, kc * 64 + r4 * 16));
        acc[0][nf] = __builtin_amdgcn_mfma_f32_16x16x32_bf16(a0, bb, acc[0][nf], 0, 0, 0);
        acc[1][nf] = __builtin_amdgcn_mfma_f32_16x16x32_bf16(a1, bb, acc[1][nf], 0, 0, 0);
      }
    }
  }

  float bv[4];
#pragma unroll
  for (int nf = 0; nf < 4; ++nf) bv[nf] = bias[n0 + nf * 16 + c];
#pragma unroll
  for (int g = 0; g < 2; ++g) {
#pragma unroll
    for (int reg = 0; reg < 4; ++reg) {
      int row = row0 + wv * 32 + g * 16 + r4 * 4 + reg;
#pragma unroll
      for (int nf = 0; nf < 4; ++nf)
        out[(size_t)row * Cc + n0 + nf * 16 + c] = acc[g][nf][reg] + bv[nf];
    }
  }
}

extern "C" void kernel_launch(void* const* d_in, const int* in_sizes, int n_in,
                              void* d_out, int out_size, void* d_ws, size_t ws_size,
                              hipStream_t stream) {
  const float* x      = (const float*)d_in[0];
  const float* qkv_w  = (const float*)d_in[1];
  const float* qkv_b  = (const float*)d_in[2];
  const float* pos_emb= (const float*)d_in[3];
  const float* ht_w   = (const float*)d_in[4];
  const float* ht_b   = (const float*)d_in[5];
  float* out = (float*)d_out;

  const size_t NQ = (size_t)BM * HW * Dd;  // 4,194,304 elements
  unsigned short* Qw = (unsigned short*)d_ws;
  unsigned short* Kw = Qw + NQ;
  unsigned short* Vw = Kw + NQ;
  unsigned short* Ow = Vw + NQ;            // bf16 O, 8 MB

  hipLaunchKernelGGL(qkv_kernel, dim3(1024), dim3(256), 0, stream,
                     x, qkv_w, qkv_b, Qw, Kw, Vw);
  hipLaunchKernelGGL(attn_kernel, dim3(512), dim3(512), 0, stream,
                     Qw, Kw, Vw, pos_emb, Ow);
  hipLaunchKernelGGL(proj_kernel, dim3(512), dim3(256), 0, stream,
                     Ow, ht_w, ht_b, out);
}